// Round 2
// baseline (135.200 us; speedup 1.0000x reference)
//
#include <hip/hip_runtime.h>
#include <hip/hip_bf16.h>

#define CROP_H 14
#define CROP_W 14
#define FM_N 4
#define FM_C 256
#define FM_H 200
#define FM_W 200
#define HW (CROP_H * CROP_W)          // 196
#define PLANE (FM_H * FM_W)           // 40000
#define CH_PER_THREAD 8
#define GROUPS (FM_C / CH_PER_THREAD) // 32

__global__ __launch_bounds__(256) void roi_align_kernel(
    const float* __restrict__ fm,      // (N, C, H, W)
    const float* __restrict__ boxes,   // (M, 4) x1,y1,x2,y2
    const int*   __restrict__ box_ind, // (M,)
    float* __restrict__ out,           // (M, C, 14, 14)
    int total)                         // M * GROUPS * HW
{
    int idx = blockIdx.x * blockDim.x + threadIdx.x;
    if (idx >= total) return;

    int ij = idx % HW;
    int t  = idx / HW;      // m*GROUPS + cg
    int cg = t % GROUPS;
    int m  = t / GROUPS;
    int i  = ij / CROP_W;
    int j  = ij % CROP_W;

    float x1 = boxes[4 * m + 0];
    float y1 = boxes[4 * m + 1];
    float x2 = boxes[4 * m + 2];
    float y2 = boxes[4 * m + 3];
    int   b  = box_ind[m];

    const float Wm1 = (float)(FM_W - 1);   // 199
    const float Hm1 = (float)(FM_H - 1);   // 199

    float spacing_w = (x2 - x1) / (float)CROP_W;
    float spacing_h = (y2 - y1) / (float)CROP_H;

    float nx0 = (x1 + spacing_w * 0.5f - 0.5f) / Wm1;
    float ny0 = (y1 + spacing_h * 0.5f - 0.5f) / Hm1;
    float nw  = spacing_w * (float)(CROP_W - 1) / Wm1;
    float nh  = spacing_h * (float)(CROP_H - 1) / Hm1;

    float gy = (float)i * (1.0f / 13.0f);
    float gx = (float)j * (1.0f / 13.0f);

    float sy = ny0 + nh * gy;
    float sx = nx0 + nw * gx;
    float py = sy * Hm1;
    float px = sx * Wm1;

    float y0f = floorf(py);
    float x0f = floorf(px);
    float wy = py - y0f;
    float wx = px - x0f;
    int y0 = (int)y0f;
    int x0 = (int)x0f;
    int y1i = y0 + 1;
    int x1i = x0 + 1;

    float v00ok = (y0  >= 0 && y0  < FM_H && x0  >= 0 && x0  < FM_W) ? 1.0f : 0.0f;
    float v01ok = (y0  >= 0 && y0  < FM_H && x1i >= 0 && x1i < FM_W) ? 1.0f : 0.0f;
    float v10ok = (y1i >= 0 && y1i < FM_H && x0  >= 0 && x0  < FM_W) ? 1.0f : 0.0f;
    float v11ok = (y1i >= 0 && y1i < FM_H && x1i >= 0 && x1i < FM_W) ? 1.0f : 0.0f;

    float w00 = (1.0f - wy) * (1.0f - wx) * v00ok;
    float w01 = (1.0f - wy) * wx          * v01ok;
    float w10 = wy          * (1.0f - wx) * v10ok;
    float w11 = wy          * wx          * v11ok;

    int y0c = min(max(y0,  0), FM_H - 1);
    int y1c = min(max(y1i, 0), FM_H - 1);
    int x0c = min(max(x0,  0), FM_W - 1);
    int x1c = min(max(x1i, 0), FM_W - 1);

    // 32-bit element offsets into fm (max index ~41M, fits easily)
    unsigned base = ((unsigned)b * FM_C + (unsigned)(cg * CH_PER_THREAD)) * PLANE;
    unsigned o00 = base + (unsigned)(y0c * FM_W + x0c);
    unsigned o01 = base + (unsigned)(y0c * FM_W + x1c);
    unsigned o10 = base + (unsigned)(y1c * FM_W + x0c);
    unsigned o11 = base + (unsigned)(y1c * FM_W + x1c);

    float* outp = out + (size_t)(m * FM_C + cg * CH_PER_THREAD) * HW + ij;

#pragma unroll
    for (int k = 0; k < CH_PER_THREAD; ++k) {
        float v00 = fm[o00];
        float v01 = fm[o01];
        float v10 = fm[o10];
        float v11 = fm[o11];
        float r = v00 * w00 + v01 * w01 + v10 * w10 + v11 * w11;
        __builtin_nontemporal_store(r, outp);
        o00 += PLANE; o01 += PLANE; o10 += PLANE; o11 += PLANE;
        outp += HW;
    }
}

extern "C" void kernel_launch(void* const* d_in, const int* in_sizes, int n_in,
                              void* d_out, int out_size, void* d_ws, size_t ws_size,
                              hipStream_t stream) {
    const float* fm      = (const float*)d_in[0];
    const float* boxes   = (const float*)d_in[1];
    const int*   box_ind = (const int*)d_in[2];
    float* out = (float*)d_out;

    int total = out_size / CH_PER_THREAD; // M * GROUPS * HW
    int block = 256;
    int grid = (total + block - 1) / block;
    roi_align_kernel<<<grid, block, 0, stream>>>(fm, boxes, box_ind, out, total);
}

// Round 3
// 109.169 us; speedup vs baseline: 1.2385x; 1.2385x over previous
//
#include <hip/hip_runtime.h>
#include <hip/hip_bf16.h>
#include <hip/hip_fp16.h>

#define FM_N 4
#define FM_C 256
#define FM_H 200
#define FM_W 200
#define CROP_H 14
#define CROP_W 14
#define HW 196                       // 14*14
#define M_BOXES 512
#define NSAMP (M_BOXES * HW)         // 100352
#define PLANE (FM_H * FM_W)          // 40000
#define LDS_STRIDE 204               // padded row stride in elements (204 % 32 != 0)
#define PLANE_LDS_BYTES (LDS_STRIDE * FM_H * 2)   // 81600 B per f16 plane
#define CH_PER_BLOCK 2
#define MAIN_LDS (CH_PER_BLOCK * PLANE_LDS_BYTES) // 163200 <= 163840
#define OUT_CH_STRIDE (FM_C * HW)    // 50176

// ---------------- kernel 0: deterministic per-image box lists ----------------
// hdr layout (ints): [0..3]=cnt[n], [4..7]=off[n], [8..519]=rank[m]
__global__ void build_lists_kernel(const int* __restrict__ box_ind, int* __restrict__ hdr) {
    int tid = threadIdx.x;
    if (tid < FM_N) {
        int cnt = 0;
        for (int m = 0; m < M_BOXES; ++m) {
            if (box_ind[m] == tid) { hdr[8 + m] = cnt; ++cnt; }
        }
        hdr[tid] = cnt;
    }
    __syncthreads();
    if (tid == 0) {
        int acc = 0;
        for (int n = 0; n < FM_N; ++n) { hdr[4 + n] = acc; acc += hdr[n]; }
    }
}

__device__ __forceinline__ unsigned pack2h(float a, float b) {
    unsigned lo = (unsigned)__half_as_ushort(__float2half_rn(a));
    unsigned hi = (unsigned)__half_as_ushort(__float2half_rn(b));
    return lo | (hi << 16);
}

// ---------------- kernel 1: per-sample records (grouped by image) ----------------
__global__ __launch_bounds__(256) void records_kernel(
    const float* __restrict__ boxes, const int* __restrict__ box_ind,
    const int* __restrict__ hdr,
    uint2* __restrict__ wrec,        // 4 x f16 weights
    uint2* __restrict__ orec,        // 4 x u16 LDS element offsets
    unsigned* __restrict__ outw)     // output word: m*OUT_CH_STRIDE + ij
{
    int g = blockIdx.x * 256 + threadIdx.x;
    if (g >= NSAMP) return;
    int m  = g / HW;
    int ij = g - m * HW;
    int i  = ij / CROP_W;
    int j  = ij - i * CROP_W;

    float x1 = boxes[4 * m + 0];
    float y1 = boxes[4 * m + 1];
    float x2 = boxes[4 * m + 2];
    float y2 = boxes[4 * m + 3];

    const float Wm1 = (float)(FM_W - 1);
    const float Hm1 = (float)(FM_H - 1);

    float spacing_w = (x2 - x1) / (float)CROP_W;
    float spacing_h = (y2 - y1) / (float)CROP_H;
    float nx0 = (x1 + spacing_w * 0.5f - 0.5f) / Wm1;
    float ny0 = (y1 + spacing_h * 0.5f - 0.5f) / Hm1;
    float nw  = spacing_w * (float)(CROP_W - 1) / Wm1;
    float nh  = spacing_h * (float)(CROP_H - 1) / Hm1;

    float gy = (float)i * (1.0f / 13.0f);
    float gx = (float)j * (1.0f / 13.0f);
    float py = (ny0 + nh * gy) * Hm1;
    float px = (nx0 + nw * gx) * Wm1;

    float y0f = floorf(py);
    float x0f = floorf(px);
    float wy = py - y0f;
    float wx = px - x0f;
    int y0 = (int)y0f, x0 = (int)x0f;
    int y1i = y0 + 1, x1i = x0 + 1;

    float v00 = (y0  >= 0 && y0  < FM_H && x0  >= 0 && x0  < FM_W) ? 1.0f : 0.0f;
    float v01 = (y0  >= 0 && y0  < FM_H && x1i >= 0 && x1i < FM_W) ? 1.0f : 0.0f;
    float v10 = (y1i >= 0 && y1i < FM_H && x0  >= 0 && x0  < FM_W) ? 1.0f : 0.0f;
    float v11 = (y1i >= 0 && y1i < FM_H && x1i >= 0 && x1i < FM_W) ? 1.0f : 0.0f;

    float w00 = (1.0f - wy) * (1.0f - wx) * v00;
    float w01 = (1.0f - wy) * wx          * v01;
    float w10 = wy          * (1.0f - wx) * v10;
    float w11 = wy          * wx          * v11;

    int y0c = min(max(y0,  0), FM_H - 1);
    int y1c = min(max(y1i, 0), FM_H - 1);
    int x0c = min(max(x0,  0), FM_W - 1);
    int x1c = min(max(x1i, 0), FM_W - 1);

    unsigned o00 = (unsigned)(y0c * LDS_STRIDE + x0c);
    unsigned o01 = (unsigned)(y0c * LDS_STRIDE + x1c);
    unsigned o10 = (unsigned)(y1c * LDS_STRIDE + x0c);
    unsigned o11 = (unsigned)(y1c * LDS_STRIDE + x1c);

    int n = box_ind[m];
    int slot = (hdr[4 + n] + hdr[8 + m]) * HW + ij;

    wrec[slot] = make_uint2(pack2h(w00, w01), pack2h(w10, w11));
    orec[slot] = make_uint2(o00 | (o01 << 16), o10 | (o11 << 16));
    outw[slot] = (unsigned)(m * OUT_CH_STRIDE + ij);
}

// ---------------- kernel 2: main — stage 2 f16 planes in LDS, gather from LDS ----
__global__ __launch_bounds__(512) void roi_main_kernel(
    const float* __restrict__ fm, const int* __restrict__ hdr,
    const uint2* __restrict__ wrec, const uint2* __restrict__ orec,
    const unsigned* __restrict__ outw, float* __restrict__ out)
{
    extern __shared__ char smem[];
    const int bid = blockIdx.x;
    const int n   = bid >> 7;                 // 128 channel-pair blocks per image
    const int c0  = (bid & 127) * CH_PER_BLOCK;
    const int tid = threadIdx.x;

    // ---- stage: 2 planes f32 -> f16 into LDS (padded row stride) ----
    const int F4_PER_PLANE = FM_H * (FM_W / 4);   // 10000 float4 per plane
    for (int t = tid; t < CH_PER_BLOCK * F4_PER_PLANE; t += 512) {
        int k   = t / F4_PER_PLANE;
        int tt  = t - k * F4_PER_PLANE;
        int row = tt / 50;
        int q   = tt - row * 50;
        const float4 v = *(const float4*)(fm
            + (size_t)(n * FM_C + c0 + k) * PLANE + row * FM_W + q * 4);
        uint2 h;
        h.x = pack2h(v.x, v.y);
        h.y = pack2h(v.z, v.w);
        *(uint2*)(smem + k * PLANE_LDS_BYTES + row * (LDS_STRIDE * 2) + q * 8) = h;
    }
    __syncthreads();

    const int nb    = hdr[n];
    const int rbase = hdr[4 + n] * HW;
    const int total = nb * HW;
    const __half* lds0 = (const __half*)smem;
    const __half* lds1 = (const __half*)(smem + PLANE_LDS_BYTES);

    for (int s = tid; s < total; s += 512) {
        uint2 wp = wrec[rbase + s];
        uint2 op = orec[rbase + s];
        unsigned ow = outw[rbase + s];

        float w00 = __half2float(__ushort_as_half((unsigned short)(wp.x & 0xffff)));
        float w01 = __half2float(__ushort_as_half((unsigned short)(wp.x >> 16)));
        float w10 = __half2float(__ushort_as_half((unsigned short)(wp.y & 0xffff)));
        float w11 = __half2float(__ushort_as_half((unsigned short)(wp.y >> 16)));

        int o00 = (int)(op.x & 0xffff);
        int o01 = (int)(op.x >> 16);
        int o10 = (int)(op.y & 0xffff);
        int o11 = (int)(op.y >> 16);

        float a00 = __half2float(lds0[o00]);
        float a01 = __half2float(lds0[o01]);
        float a10 = __half2float(lds0[o10]);
        float a11 = __half2float(lds0[o11]);
        float r0 = a00 * w00 + a01 * w01 + a10 * w10 + a11 * w11;

        float b00 = __half2float(lds1[o00]);
        float b01 = __half2float(lds1[o01]);
        float b10 = __half2float(lds1[o10]);
        float b11 = __half2float(lds1[o11]);
        float r1 = b00 * w00 + b01 * w01 + b10 * w10 + b11 * w11;

        float* outp = out + ow + (size_t)c0 * HW;
        __builtin_nontemporal_store(r0, outp);
        __builtin_nontemporal_store(r1, outp + HW);
    }
}

// ---------------- fallback (round-2 kernel) if workspace too small ----------------
#define CH_PER_THREAD 8
#define GROUPS (FM_C / CH_PER_THREAD)
__global__ __launch_bounds__(256) void roi_fallback_kernel(
    const float* __restrict__ fm, const float* __restrict__ boxes,
    const int* __restrict__ box_ind, float* __restrict__ out, int total)
{
    int idx = blockIdx.x * blockDim.x + threadIdx.x;
    if (idx >= total) return;
    int ij = idx % HW;
    int t  = idx / HW;
    int cg = t % GROUPS;
    int m  = t / GROUPS;
    int i  = ij / CROP_W;
    int j  = ij % CROP_W;
    float x1 = boxes[4*m+0], y1 = boxes[4*m+1], x2 = boxes[4*m+2], y2 = boxes[4*m+3];
    int b = box_ind[m];
    const float Wm1 = (float)(FM_W-1), Hm1 = (float)(FM_H-1);
    float spacing_w = (x2-x1)/(float)CROP_W, spacing_h = (y2-y1)/(float)CROP_H;
    float nx0 = (x1 + spacing_w*0.5f - 0.5f)/Wm1;
    float ny0 = (y1 + spacing_h*0.5f - 0.5f)/Hm1;
    float nw = spacing_w*(float)(CROP_W-1)/Wm1, nh = spacing_h*(float)(CROP_H-1)/Hm1;
    float py = (ny0 + nh*((float)i*(1.0f/13.0f)))*Hm1;
    float px = (nx0 + nw*((float)j*(1.0f/13.0f)))*Wm1;
    float y0f = floorf(py), x0f = floorf(px);
    float wy = py-y0f, wx = px-x0f;
    int y0 = (int)y0f, x0 = (int)x0f, y1i = y0+1, x1i = x0+1;
    float v00 = (y0>=0 && y0<FM_H && x0>=0 && x0<FM_W) ? 1.f : 0.f;
    float v01 = (y0>=0 && y0<FM_H && x1i>=0 && x1i<FM_W) ? 1.f : 0.f;
    float v10 = (y1i>=0 && y1i<FM_H && x0>=0 && x0<FM_W) ? 1.f : 0.f;
    float v11 = (y1i>=0 && y1i<FM_H && x1i>=0 && x1i<FM_W) ? 1.f : 0.f;
    float w00 = (1.f-wy)*(1.f-wx)*v00, w01 = (1.f-wy)*wx*v01;
    float w10 = wy*(1.f-wx)*v10, w11 = wy*wx*v11;
    int y0c = min(max(y0,0),FM_H-1), y1c = min(max(y1i,0),FM_H-1);
    int x0c = min(max(x0,0),FM_W-1), x1c = min(max(x1i,0),FM_W-1);
    unsigned base = ((unsigned)b*FM_C + (unsigned)(cg*CH_PER_THREAD))*PLANE;
    unsigned o00 = base + (unsigned)(y0c*FM_W+x0c);
    unsigned o01 = base + (unsigned)(y0c*FM_W+x1c);
    unsigned o10 = base + (unsigned)(y1c*FM_W+x0c);
    unsigned o11 = base + (unsigned)(y1c*FM_W+x1c);
    float* outp = out + (size_t)(m*FM_C + cg*CH_PER_THREAD)*HW + ij;
#pragma unroll
    for (int k = 0; k < CH_PER_THREAD; ++k) {
        float r = fm[o00]*w00 + fm[o01]*w01 + fm[o10]*w10 + fm[o11]*w11;
        __builtin_nontemporal_store(r, outp);
        o00 += PLANE; o01 += PLANE; o10 += PLANE; o11 += PLANE;
        outp += HW;
    }
}

extern "C" void kernel_launch(void* const* d_in, const int* in_sizes, int n_in,
                              void* d_out, int out_size, void* d_ws, size_t ws_size,
                              hipStream_t stream) {
    const float* fm      = (const float*)d_in[0];
    const float* boxes   = (const float*)d_in[1];
    const int*   box_ind = (const int*)d_in[2];
    float* out = (float*)d_out;

    const size_t HDR_BYTES  = 4096;
    const size_t WREC_BYTES = (size_t)NSAMP * 8;
    const size_t OREC_BYTES = (size_t)NSAMP * 8;
    const size_t OUTW_BYTES = (size_t)NSAMP * 4;
    const size_t need = HDR_BYTES + WREC_BYTES + OREC_BYTES + OUTW_BYTES; // ~2.01 MB

    if (ws_size < need) {
        int total = out_size / CH_PER_THREAD;
        int grid = (total + 255) / 256;
        roi_fallback_kernel<<<grid, 256, 0, stream>>>(fm, boxes, box_ind, out, total);
        return;
    }

    int*      hdr   = (int*)d_ws;
    uint2*    wrec  = (uint2*)((char*)d_ws + HDR_BYTES);
    uint2*    orec  = (uint2*)((char*)d_ws + HDR_BYTES + WREC_BYTES);
    unsigned* outwp = (unsigned*)((char*)d_ws + HDR_BYTES + WREC_BYTES + OREC_BYTES);

    build_lists_kernel<<<1, 64, 0, stream>>>(box_ind, hdr);
    records_kernel<<<NSAMP / 256, 256, 0, stream>>>(boxes, box_ind, hdr, wrec, orec, outwp);

    hipFuncSetAttribute((const void*)roi_main_kernel,
                        hipFuncAttributeMaxDynamicSharedMemorySize, MAIN_LDS);
    roi_main_kernel<<<FM_N * 128, 512, MAIN_LDS, stream>>>(fm, hdr, wrec, orec, outwp, out);
}

// Round 4
// 90.427 us; speedup vs baseline: 1.4951x; 1.2073x over previous
//
#include <hip/hip_runtime.h>
#include <hip/hip_bf16.h>
#include <hip/hip_fp16.h>

#define FM_N 4
#define FM_C 256
#define FM_H 200
#define FM_W 200
#define CROP_H 14
#define CROP_W 14
#define HW 196
#define M_BOXES 512
#define NSAMP (M_BOXES * HW)      // 100352
#define NROWS (M_BOXES * CROP_H)  // 7168
#define PLANE (FM_H * FM_W)       // 40000
#define OUT_CH_STRIDE (FM_C * HW) // 50176
#define QROWS 51                  // staged rows per quarter (h<3), h==3 uses 50
#define K3_LDS (QROWS * FM_W * 8) // 81600 B: [pixel][4ch] f16

// ws layout
#define WS_ROWBIN   0         // u8[7168]
#define WS_ROWRANK  8192      // i32[7168]
#define WS_COUNTS   36864     // i32[16]
#define WS_BASES    36928     // i32[16]
#define WS_RECS     40960     // uint4[NSAMP*2]  (interleaved: [w f32x4][offs,outw])
#define WS_NEED     (WS_RECS + (size_t)NSAMP * 32)

__device__ __forceinline__ unsigned pack2h(float a, float b) {
    unsigned lo = (unsigned)__half_as_ushort(__float2half_rn(a));
    unsigned hi = (unsigned)__half_as_ushort(__float2half_rn(b));
    return lo | (hi << 16);
}
__device__ __forceinline__ float cvlo(unsigned u) {
    __half2 h = __builtin_bit_cast(__half2, u); return __low2float(h);
}
__device__ __forceinline__ float cvhi(unsigned u) {
    __half2 h = __builtin_bit_cast(__half2, u); return __high2float(h);
}

// ---------- K0: per crop-row bin id (image*4 + y-quarter) ----------
__global__ __launch_bounds__(256) void k0_rowbin(
    const float* __restrict__ boxes, const int* __restrict__ box_ind,
    unsigned char* __restrict__ rowbin)
{
    int r = blockIdx.x * 256 + threadIdx.x;
    if (r >= NROWS) return;
    int m = r / CROP_H, i = r - m * CROP_H;
    float y1 = boxes[4 * m + 1], y2 = boxes[4 * m + 3];
    float sh  = (y2 - y1) / (float)CROP_H;
    float ny0 = (y1 + sh * 0.5f - 0.5f) / 199.0f;
    float nh  = sh * 13.0f / 199.0f;
    float py  = (ny0 + nh * ((float)i * (1.0f / 13.0f))) * 199.0f;
    int y0  = (int)floorf(py);
    int y0c = min(max(y0, 0), FM_H - 1);
    int h = (y0c < 50) ? 0 : (y0c < 100) ? 1 : (y0c < 150) ? 2 : 3;
    rowbin[r] = (unsigned char)(box_ind[m] * 4 + h);
}

// ---------- K1: deterministic rank-within-bin + counts + bases ----------
__global__ __launch_bounds__(1024) void k1_binscan(
    const unsigned char* __restrict__ rowbin, int* __restrict__ rowrank,
    int* __restrict__ counts, int* __restrict__ bases)
{
    __shared__ int scnt[16], sbase[16];
    int tid = threadIdx.x;
    int w = tid >> 6, lane = tid & 63;
    unsigned long long lm = (lane == 63) ? 0x7fffffffffffffffull : ((1ull << lane) - 1ull);
    int cnt = 0;
    for (int k = 0; k < NROWS; k += 512) {
        int b[8];
#pragma unroll
        for (int q = 0; q < 8; ++q) b[q] = rowbin[k + q * 64 + lane];
#pragma unroll
        for (int q = 0; q < 8; ++q) {
            bool match = (b[q] == w);
            unsigned long long bal = __ballot(match);
            if (match) rowrank[k + q * 64 + lane] = cnt + (int)__popcll(bal & lm);
            cnt += (int)__popcll(bal);
        }
    }
    if (lane == 0) scnt[w] = cnt;
    __syncthreads();
    if (tid == 0) { int acc = 0; for (int q = 0; q < 16; ++q) { sbase[q] = acc; acc += scnt[q]; } }
    __syncthreads();
    if (tid < 16) { counts[tid] = scnt[tid]; bases[tid] = sbase[tid]; }
}

// ---------- K2: per-sample records, ordered by (bin, row-rank, j) ----------
__global__ __launch_bounds__(256) void k2_records(
    const float* __restrict__ boxes,
    const unsigned char* __restrict__ rowbin, const int* __restrict__ rowrank,
    const int* __restrict__ bases, uint4* __restrict__ recs)
{
    int g = blockIdx.x * 256 + threadIdx.x;
    if (g >= NSAMP) return;
    int m  = g / HW;
    int ij = g - m * HW;
    int i  = ij / CROP_W;
    int j  = ij - i * CROP_W;

    float x1 = boxes[4 * m + 0], y1 = boxes[4 * m + 1];
    float x2 = boxes[4 * m + 2], y2 = boxes[4 * m + 3];

    float sw = (x2 - x1) / (float)CROP_W;
    float sh = (y2 - y1) / (float)CROP_H;
    float nx0 = (x1 + sw * 0.5f - 0.5f) / 199.0f;
    float ny0 = (y1 + sh * 0.5f - 0.5f) / 199.0f;
    float nw = sw * 13.0f / 199.0f;
    float nh = sh * 13.0f / 199.0f;

    float py = (ny0 + nh * ((float)i * (1.0f / 13.0f))) * 199.0f;
    float px = (nx0 + nw * ((float)j * (1.0f / 13.0f))) * 199.0f;

    float y0f = floorf(py), x0f = floorf(px);
    float wy = py - y0f, wx = px - x0f;
    int y0 = (int)y0f, x0 = (int)x0f;
    int y1i = y0 + 1, x1i = x0 + 1;

    float v00 = (y0  >= 0 && y0  < FM_H && x0  >= 0 && x0  < FM_W) ? 1.0f : 0.0f;
    float v01 = (y0  >= 0 && y0  < FM_H && x1i >= 0 && x1i < FM_W) ? 1.0f : 0.0f;
    float v10 = (y1i >= 0 && y1i < FM_H && x0  >= 0 && x0  < FM_W) ? 1.0f : 0.0f;
    float v11 = (y1i >= 0 && y1i < FM_H && x1i >= 0 && x1i < FM_W) ? 1.0f : 0.0f;

    float w00 = (1.0f - wy) * (1.0f - wx) * v00;
    float w01 = (1.0f - wy) * wx          * v01;
    float w10 = wy          * (1.0f - wx) * v10;
    float w11 = wy          * wx          * v11;

    int y0c = min(max(y0,  0), FM_H - 1);
    int y1c = min(max(y1i, 0), FM_H - 1);
    int x0c = min(max(x0,  0), FM_W - 1);
    int x1c = min(max(x1i, 0), FM_W - 1);

    int row = m * CROP_H + i;
    int bin = rowbin[row];
    int h   = bin & 3;
    int ly0 = y0c - h * 50;
    int ly1 = y1c - h * 50;

    unsigned o00 = (unsigned)(ly0 * FM_W + x0c);
    unsigned o01 = (unsigned)(ly0 * FM_W + x1c);
    unsigned o10 = (unsigned)(ly1 * FM_W + x0c);
    unsigned o11 = (unsigned)(ly1 * FM_W + x1c);

    int slot = (bases[bin] + rowrank[row]) * CROP_W + j;

    float4 wv = make_float4(w00, w01, w10, w11);
    recs[2 * slot]     = __builtin_bit_cast(uint4, wv);
    recs[2 * slot + 1] = make_uint4(o00 | (o01 << 16), o10 | (o11 << 16),
                                    (unsigned)(m * OUT_CH_STRIDE + ij), 0u);
}

// ---------- K3: main — stage quarter-plane x 4ch as interleaved f16, gather ----------
__global__ __launch_bounds__(512) void k3_main(
    const float* __restrict__ fm, const uint4* __restrict__ recs,
    const int* __restrict__ counts, const int* __restrict__ bases,
    float* __restrict__ out)
{
    extern __shared__ char smem[];
    const int bid  = blockIdx.x;
    const int quad = bid & 63;
    const int h    = (bid >> 6) & 3;
    const int n    = bid >> 8;
    const int tid  = threadIdx.x;

    const int rows = (h == 3) ? 50 : 51;
    const int npairs = rows * (FM_W / 2);   // 2-pixel groups
    const float* p0 = fm + (size_t)(n * FM_C + quad * 4) * PLANE + h * 50 * FM_W;

    for (int t = tid; t < npairs; t += 512) {
        int px = t * 2;
        float2 a = *(const float2*)(p0 + px);
        float2 b = *(const float2*)(p0 + PLANE + px);
        float2 c = *(const float2*)(p0 + 2 * PLANE + px);
        float2 d = *(const float2*)(p0 + 3 * PLANE + px);
        uint4 wv;
        wv.x = pack2h(a.x, b.x);   // px:   c0,c1
        wv.y = pack2h(c.x, d.x);   // px:   c2,c3
        wv.z = pack2h(a.y, b.y);   // px+1: c0,c1
        wv.w = pack2h(c.y, d.y);   // px+1: c2,c3
        *(uint4*)(smem + (size_t)px * 8) = wv;
    }
    __syncthreads();

    const int bin   = n * 4 + h;
    const int cnt   = counts[bin];
    const int total = cnt * CROP_W;
    const uint4* rp = recs + 2 * (size_t)(bases[bin] * CROP_W);
    float* outq = out + quad * 4 * HW;

#pragma unroll 2
    for (int s = tid; s < total; s += 512) {
        uint4 wa = rp[2 * s];
        uint4 ob = rp[2 * s + 1];
        float w00 = __uint_as_float(wa.x);
        float w01 = __uint_as_float(wa.y);
        float w10 = __uint_as_float(wa.z);
        float w11 = __uint_as_float(wa.w);
        unsigned o00 = ob.x & 0xffffu, o01 = ob.x >> 16;
        unsigned o10 = ob.y & 0xffffu, o11 = ob.y >> 16;

        uint2 t00 = *(const uint2*)(smem + (size_t)o00 * 8);
        uint2 t01 = *(const uint2*)(smem + (size_t)o01 * 8);
        uint2 t10 = *(const uint2*)(smem + (size_t)o10 * 8);
        uint2 t11 = *(const uint2*)(smem + (size_t)o11 * 8);

        float r0 = cvlo(t00.x) * w00 + cvlo(t01.x) * w01 + cvlo(t10.x) * w10 + cvlo(t11.x) * w11;
        float r1 = cvhi(t00.x) * w00 + cvhi(t01.x) * w01 + cvhi(t10.x) * w10 + cvhi(t11.x) * w11;
        float r2 = cvlo(t00.y) * w00 + cvlo(t01.y) * w01 + cvlo(t10.y) * w10 + cvlo(t11.y) * w11;
        float r3 = cvhi(t00.y) * w00 + cvhi(t01.y) * w01 + cvhi(t10.y) * w10 + cvhi(t11.y) * w11;

        float* op = outq + ob.z;
        __builtin_nontemporal_store(r0, op);
        __builtin_nontemporal_store(r1, op + HW);
        __builtin_nontemporal_store(r2, op + 2 * HW);
        __builtin_nontemporal_store(r3, op + 3 * HW);
    }
}

// ---------- fallback (round-2 kernel) if workspace too small ----------
#define CH_PER_THREAD 8
#define GROUPS (FM_C / CH_PER_THREAD)
__global__ __launch_bounds__(256) void roi_fallback_kernel(
    const float* __restrict__ fm, const float* __restrict__ boxes,
    const int* __restrict__ box_ind, float* __restrict__ out, int total)
{
    int idx = blockIdx.x * blockDim.x + threadIdx.x;
    if (idx >= total) return;
    int ij = idx % HW;
    int t  = idx / HW;
    int cg = t % GROUPS;
    int m  = t / GROUPS;
    int i  = ij / CROP_W;
    int j  = ij % CROP_W;
    float x1 = boxes[4*m+0], y1 = boxes[4*m+1], x2 = boxes[4*m+2], y2 = boxes[4*m+3];
    int b = box_ind[m];
    float sw = (x2-x1)/(float)CROP_W, sh = (y2-y1)/(float)CROP_H;
    float nx0 = (x1 + sw*0.5f - 0.5f)/199.f;
    float ny0 = (y1 + sh*0.5f - 0.5f)/199.f;
    float nw = sw*13.f/199.f, nh = sh*13.f/199.f;
    float py = (ny0 + nh*((float)i*(1.0f/13.0f)))*199.f;
    float px = (nx0 + nw*((float)j*(1.0f/13.0f)))*199.f;
    float y0f = floorf(py), x0f = floorf(px);
    float wy = py-y0f, wx = px-x0f;
    int y0 = (int)y0f, x0 = (int)x0f, y1i = y0+1, x1i = x0+1;
    float v00 = (y0>=0 && y0<FM_H && x0>=0 && x0<FM_W) ? 1.f : 0.f;
    float v01 = (y0>=0 && y0<FM_H && x1i>=0 && x1i<FM_W) ? 1.f : 0.f;
    float v10 = (y1i>=0 && y1i<FM_H && x0>=0 && x0<FM_W) ? 1.f : 0.f;
    float v11 = (y1i>=0 && y1i<FM_H && x1i>=0 && x1i<FM_W) ? 1.f : 0.f;
    float w00 = (1.f-wy)*(1.f-wx)*v00, w01 = (1.f-wy)*wx*v01;
    float w10 = wy*(1.f-wx)*v10, w11 = wy*wx*v11;
    int y0c = min(max(y0,0),FM_H-1), y1c = min(max(y1i,0),FM_H-1);
    int x0c = min(max(x0,0),FM_W-1), x1c = min(max(x1i,0),FM_W-1);
    unsigned base = ((unsigned)b*FM_C + (unsigned)(cg*CH_PER_THREAD))*PLANE;
    unsigned o00 = base + (unsigned)(y0c*FM_W+x0c);
    unsigned o01 = base + (unsigned)(y0c*FM_W+x1c);
    unsigned o10 = base + (unsigned)(y1c*FM_W+x0c);
    unsigned o11 = base + (unsigned)(y1c*FM_W+x1c);
    float* outp = out + (size_t)(m*FM_C + cg*CH_PER_THREAD)*HW + ij;
#pragma unroll
    for (int k = 0; k < CH_PER_THREAD; ++k) {
        float r = fm[o00]*w00 + fm[o01]*w01 + fm[o10]*w10 + fm[o11]*w11;
        __builtin_nontemporal_store(r, outp);
        o00 += PLANE; o01 += PLANE; o10 += PLANE; o11 += PLANE;
        outp += HW;
    }
}

extern "C" void kernel_launch(void* const* d_in, const int* in_sizes, int n_in,
                              void* d_out, int out_size, void* d_ws, size_t ws_size,
                              hipStream_t stream) {
    const float* fm      = (const float*)d_in[0];
    const float* boxes   = (const float*)d_in[1];
    const int*   box_ind = (const int*)d_in[2];
    float* out = (float*)d_out;

    if (ws_size < WS_NEED) {
        int total = out_size / CH_PER_THREAD;
        int grid = (total + 255) / 256;
        roi_fallback_kernel<<<grid, 256, 0, stream>>>(fm, boxes, box_ind, out, total);
        return;
    }

    unsigned char* rowbin = (unsigned char*)d_ws + WS_ROWBIN;
    int*   rowrank = (int*)((char*)d_ws + WS_ROWRANK);
    int*   counts  = (int*)((char*)d_ws + WS_COUNTS);
    int*   bases   = (int*)((char*)d_ws + WS_BASES);
    uint4* recs    = (uint4*)((char*)d_ws + WS_RECS);

    k0_rowbin<<<NROWS / 256, 256, 0, stream>>>(boxes, box_ind, rowbin);
    k1_binscan<<<1, 1024, 0, stream>>>(rowbin, rowrank, counts, bases);
    k2_records<<<NSAMP / 256, 256, 0, stream>>>(boxes, rowbin, rowrank, bases, recs);

    hipFuncSetAttribute((const void*)k3_main,
                        hipFuncAttributeMaxDynamicSharedMemorySize, K3_LDS);
    k3_main<<<FM_N * 4 * 64, 512, K3_LDS, stream>>>(fm, recs, counts, bases, out);
}